// Round 3
// baseline (59442.249 us; speedup 1.0000x reference)
//
#include <hip/hip_runtime.h>
#include <math.h>

typedef __attribute__((ext_vector_type(2))) double f64x2;
typedef __attribute__((ext_vector_type(2))) float f32x2;
typedef __attribute__((ext_vector_type(4))) float f32x4;

// ---------------- Wp -> wTr fp32, layout [t][n][ci] -----------------------------
// Value = raw fp32 Wp entry; conversion to f64 happens at use ((double)f32 is
// exact), so the conv2 products are bit-identical to the R11 fp64 chain.
__global__ __launch_bounds__(256) void k_w64t(const float* __restrict__ Wp,
                                              float* __restrict__ wTr) {
  int gid = blockIdx.x * 256 + threadIdx.x;  // 81*256*256 = 5,308,416
  int ci = gid & 255;
  int n = (gid >> 8) & 255;
  int t = gid >> 16;
  wTr[gid] = Wp[(size_t)n * 20736 + ci * 81 + t];
}

// ---------------- Conv1: 1->256 k9 s1, fp64, out [b][y][x][256], 19x19 ----------
// Row/col 19 of the 20x20 output are never read by the stride-2 9x9 conv2
// (2*oh2+ky <= 18). Inner fma chain identical to the R11 kernel -> bit-same h.
__global__ __launch_bounds__(256) void k_conv1_19(const float* __restrict__ x,
                                                  const float* __restrict__ Wc,
                                                  const float* __restrict__ bc,
                                                  double* __restrict__ h) {
  int b = blockIdx.x >> 1;
  int rh = (blockIdx.x & 1) * 10;
  int re = rh ? 19 : 10;
  int oc = threadIdx.x;
  __shared__ float xs[784];
  for (int i = threadIdx.x; i < 784; i += 256) xs[i] = x[(size_t)b * 784 + i];
  __syncthreads();
  float w[81];
#pragma unroll
  for (int t = 0; t < 81; t++) w[t] = Wc[(size_t)oc * 81 + t];
  double bias = (double)bc[oc];
  for (int oh = rh; oh < re; oh++) {
    for (int ow4 = 0; ow4 < 20; ow4 += 4) {
      double a0 = bias, a1 = bias, a2 = bias, a3 = bias;
#pragma unroll
      for (int ky = 0; ky < 9; ky++) {
        const float* xr = &xs[(oh + ky) * 28 + ow4];
#pragma unroll
        for (int kx = 0; kx < 9; kx++) {
          double wv = (double)w[ky * 9 + kx];
          a0 += wv * (double)xr[kx + 0];
          a1 += wv * (double)xr[kx + 1];
          a2 += wv * (double)xr[kx + 2];
          a3 += wv * (double)xr[kx + 3];
        }
      }
      size_t base = ((size_t)(b * 19 + oh) * 19 + ow4) * 256 + oc;
      h[base + 0]   = fmax(a0, 0.0);
      h[base + 256] = fmax(a1, 0.0);
      h[base + 512] = fmax(a2, 0.0);
      if (ow4 < 16) h[base + 768] = fmax(a3, 0.0);  // skip col 19
    }
  }
}

// ---------------- Conv2: global-direct fp64 VALU, 1 wave = 1 image x 32 ch ------
// Per-output accumulation: k = (ky*9+kx)*256 + ci ASCENDING, sequential fma
// chain -> bit-identical to the R11 passing kernel (chaos-safe).
// Grid: imgs*8 blocks of 64 threads; quarter = 1024 blocks = 1 wave/SIMD exact.
// lane grid 4(lm) x 16(ln): thread owns sp rows lm*9+i (i<9), ch n0+ln*2+j (j<2).
__global__ __launch_bounds__(64) void k_conv2_v(const double* __restrict__ h,
                                                const float* __restrict__ wTr,
                                                double* __restrict__ uraw,
                                                int img0) {
  int bx = blockIdx.x;
  int mt = bx >> 3;   // image within quarter [0,128)
  int nt = bx & 7;    // channel tile
  int n0 = nt * 32;
  int lane = threadIdx.x;
  int lm = lane >> 4;   // [0,4)
  int ln = lane & 15;   // [0,16)

  const double* h_img = h + (size_t)mt * (361 * 256);

  int rowoff[9];
#pragma unroll
  for (int i = 0; i < 9; i++) {
    int sp = lm * 9 + i;
    int oh2 = sp / 6, ow2 = sp % 6;
    rowoff[i] = (2 * oh2) * 19 + 2 * ow2;
  }

  double acc[9][2];
#pragma unroll
  for (int i = 0; i < 9; i++) { acc[i][0] = 0.0; acc[i][1] = 0.0; }

  const float* bbase = wTr + (size_t)(n0 + ln * 2) * 256;

  for (int ky = 0; ky < 9; ky++) {
    for (int kx = 0; kx < 9; kx++) {
      int koff = ky * 19 + kx;
      const double* ar[9];
#pragma unroll
      for (int i = 0; i < 9; i++) ar[i] = h_img + (size_t)(rowoff[i] + koff) * 256;
      const float* br = bbase + (size_t)(ky * 9 + kx) * 65536;
#pragma unroll 2
      for (int ci = 0; ci < 256; ci += 2) {
        f32x2 bl0 = *(const f32x2*)(br + ci);
        f32x2 bl1 = *(const f32x2*)(br + 256 + ci);
        double b00 = (double)bl0.x, b01 = (double)bl0.y;
        double b10 = (double)bl1.x, b11 = (double)bl1.y;
#pragma unroll
        for (int i = 0; i < 9; i++) {
          f64x2 av = *(const f64x2*)(ar[i] + ci);
          acc[i][0] = fma(av.x, b00, acc[i][0]);
          acc[i][0] = fma(av.y, b01, acc[i][0]);
          acc[i][1] = fma(av.x, b10, acc[i][1]);
          acc[i][1] = fma(av.y, b11, acc[i][1]);
        }
      }
    }
  }

  // out[b][ch][sp]: capsule features = 8 consecutive doubles (ch*36+sp = cap*8+feat)
  size_t ob = (size_t)(img0 + mt) * 9216;
#pragma unroll
  for (int i = 0; i < 9; i++) {
    int sp = lm * 9 + i;
#pragma unroll
    for (int j = 0; j < 2; j++) {
      int n = n0 + ln * 2 + j;
      uraw[ob + (size_t)n * 36 + sp] = acc[i][j];
    }
  }
}

// ---------------- squash of primary capsules, fp64, IN PLACE --------------------
// uraw is [b][ch][sp]; capsule c's features are uraw[b*9216 + c*8 .. +7].
// Same value chain as R11 (bias add, i-ascending ns sum, same scale formula).
__global__ __launch_bounds__(256) void k_squash_ip(double* __restrict__ u,
                                                   const float* __restrict__ bp) {
  int idx = blockIdx.x * 256 + threadIdx.x;  // (b,c): 512*1152
  int bl = idx / 1152, c = idx % 1152;
  size_t base = ((size_t)bl * 1152 + c) * 8;
  double v[8];
  double ns = 0.0;
#pragma unroll
  for (int i = 0; i < 8; i++) {
    int f = c * 8 + i;
    int ch = f / 36;
    double val = u[base + i] + (double)bp[ch];
    v[i] = val;
    ns += val * val;
  }
  double sc = (ns / (1.0 + ns)) / (0.001 + sqrt(ns));
#pragma unroll
  for (int i = 0; i < 8; i++) u[base + i] = v[i] * sc;
}

// ---------------- u_hat fp64, eighth batch (bl in [0,64)) -----------------------
__global__ __launch_bounds__(320) void k_uhat64(const double* __restrict__ u,
                                                const float* __restrict__ Wd,
                                                double* __restrict__ uhat, int b0) {
  int c = blockIdx.x;
  int t = threadIdx.x;
  int jo = t % 160, half = t / 160;
  double w[8];
#pragma unroll
  for (int i = 0; i < 8; i++) w[i] = (double)Wd[((size_t)c * 160 + jo) * 8 + i];
  for (int it = 0; it < 32; it++) {
    int bl = it * 2 + half;
    const double* up = u + ((size_t)(b0 + bl) * 1152 + c) * 8;
    double s = 0.0;
#pragma unroll
    for (int i = 0; i < 8; i++) s += w[i] * up[i];
    uhat[((size_t)bl * 1152 + c) * 160 + jo] = s;
  }
}

// ---------------- c_ij = softmax(b_ij) fp64, wide grid --------------------------
__global__ __launch_bounds__(192) void k_cij(const double* __restrict__ bij,
                                             double* __restrict__ cij) {
  int bl = blockIdx.x;
  int c = blockIdx.y * 192 + threadIdx.x;  // 6*192 = 1152
  const double* bp_ = bij + ((size_t)bl * 1152 + c) * 10;
  double bv[10], mx = -1e300;
#pragma unroll
  for (int j = 0; j < 10; j++) { bv[j] = bp_[j]; mx = fmax(mx, bv[j]); }
  double s = 0.0;
#pragma unroll
  for (int j = 0; j < 10; j++) { bv[j] = exp(bv[j] - mx); s += bv[j]; }
  double inv = 1.0 / s;
  double* cp = cij + ((size_t)bl * 1152 + c) * 10;
#pragma unroll
  for (int j = 0; j < 10; j++) cp[j] = bv[j] * inv;
}

// ---------------- routing s_j pass fp64, wide coalesced grid (bl x j) -----------
template <int IT>
__global__ __launch_bounds__(256) void k_route_s(const double* __restrict__ uhat,
                                                 const double* __restrict__ cij,
                                                 double* __restrict__ sj) {
  int bl = blockIdx.x, j = blockIdx.y;
  int tid = threadIdx.x;
  int o = tid & 15, cl = tid >> 4;
  double acc = 0.0;
  const double* up = uhat + (size_t)bl * 1152 * 160 + j * 16 + o;
  if (IT == 0) {
    for (int c = cl; c < 1152; c += 16) acc += 0.1 * up[(size_t)c * 160];
  } else {
    const double* cp = cij + (size_t)bl * 1152 * 10 + j;
    for (int c = cl; c < 1152; c += 16) acc += cp[(size_t)c * 10] * up[(size_t)c * 160];
  }
  __shared__ double red[256];
  red[tid] = acc;
  __syncthreads();
#pragma unroll
  for (int s = 128; s >= 16; s >>= 1) {
    if (tid < s) red[tid] += red[tid + s];
    __syncthreads();
  }
  if (tid < 16) sj[(size_t)bl * 160 + j * 16 + tid] = red[tid];
}

// ---------------- agreement update b_ij fp64, wide grid -------------------------
template <bool FIRST>
__global__ __launch_bounds__(256) void k_route_b(const double* __restrict__ uhat,
                                                 const double* __restrict__ sj,
                                                 double* __restrict__ bij) {
  __shared__ double sl[160];
  int bl = blockIdx.x;
  int tid = threadIdx.x;
  if (tid < 160) sl[tid] = sj[(size_t)bl * 160 + tid];
  __syncthreads();
  int c = blockIdx.y * 128 + (tid >> 1);
  int j0 = (tid & 1) * 5;
  const double* up = uhat + ((size_t)bl * 1152 + c) * 160;
  double* bp_ = bij + ((size_t)bl * 1152 + c) * 10;
#pragma unroll
  for (int jj = 0; jj < 5; jj++) {
    int j = j0 + jj;
    double dot = 0.0;
#pragma unroll
    for (int oo = 0; oo < 16; oo++) dot += sl[j * 16 + oo] * up[j * 16 + oo];
    bp_[j] = (FIRST ? 0.0 : bp_[j]) + dot;
  }
}

// ---------------- epilogue: np-fp32-canonical (verbatim R11 chain) --------------
__global__ __launch_bounds__(192) void k_epi(const double* __restrict__ sj,
                                             float* __restrict__ vout,
                                             float* __restrict__ idxout, int b0) {
#pragma clang fp contract(off)
  __shared__ float vsh[160];
  __shared__ float len32[10];
  int bl = blockIdx.x;
  int tid = threadIdx.x;
  const double* sp = sj + (size_t)bl * 160;
  if (tid < 10) {
    float s32[16], a[16];
#pragma unroll
    for (int o = 0; o < 16; o++) { s32[o] = (float)sp[tid * 16 + o]; a[o] = s32[o] * s32[o]; }
    float r[8];
#pragma unroll
    for (int k = 0; k < 8; k++) r[k] = a[k] + a[k + 8];
    float ns = ((r[0] + r[1]) + (r[2] + r[3])) + ((r[4] + r[5]) + (r[6] + r[7]));
    float A = ns / (1.0f + ns);
    float D = 0.001f + sqrtf(ns);
#pragma unroll
    for (int o = 0; o < 16; o++) {
      float v = A * (s32[o] / D);
      vsh[tid * 16 + o] = v;
      a[o] = v * v;
    }
#pragma unroll
    for (int k = 0; k < 8; k++) r[k] = a[k] + a[k + 8];
    float nv = ((r[0] + r[1]) + (r[2] + r[3])) + ((r[4] + r[5]) + (r[6] + r[7]));
    len32[tid] = sqrtf(nv);
  }
  __syncthreads();
  if (tid < 160) vout[(size_t)(b0 + bl) * 160 + tid] = vsh[tid];
  if (tid == 0) {
    float mx = len32[0];
    for (int jj = 1; jj < 10; jj++) mx = fmaxf(mx, len32[jj]);
    float e[10];
    for (int jj = 0; jj < 10; jj++) e[jj] = (float)exp((double)(len32[jj] - mx));
    float ssum = ((e[0] + e[1]) + (e[2] + e[3])) + ((e[4] + e[5]) + (e[6] + e[7]));
    ssum = ssum + e[8];
    ssum = ssum + e[9];
    int best = 0;
    float bst = e[0] / ssum;
    for (int jj = 1; jj < 10; jj++) {
      float p = e[jj] / ssum;
      if (p > bst) { bst = p; best = jj; }
    }
    idxout[b0 + bl] = (float)best;
  }
}

// ---------------- decoder layer 1 (masked input has only 16 nonzeros) -----------
__global__ __launch_bounds__(256) void k_z1(const float* __restrict__ vout,
                                            const int* __restrict__ targets,
                                            const float* __restrict__ W1,
                                            const float* __restrict__ b1,
                                            float* __restrict__ z1) {
  int id = blockIdx.x * 256 + threadIdx.x;
  int b = id >> 9, n = id & 511;
  int t = targets[b];
  float acc = b1[n];
  const float* wr = W1 + (size_t)n * 160 + t * 16;
  const float* vr = vout + (size_t)b * 160 + t * 16;
#pragma unroll
  for (int o = 0; o < 16; o++) acc += wr[o] * vr[o];
  z1[id] = fmaxf(acc, 0.f);
}

// ---------------- generic fp32 GEMM: out[b,n] = act(Z[b,:]·W[n,:] + bias[n]) ----
template <int ACT>
__global__ __launch_bounds__(256) void k_gemm_act(const float* __restrict__ Z,
                                                  const float* __restrict__ W,
                                                  const float* __restrict__ bias,
                                                  float* __restrict__ out, int N, int K) {
  __shared__ float Zt[64][17];
  __shared__ float Wt[64][17];
  int b0 = blockIdx.x * 64;
  int n0 = blockIdx.y * 64;
  int tid = threadIdx.x;
  int ty = tid >> 4, tx = tid & 15;
  int lr = tid >> 2, lc = (tid & 3) * 4;
  float acc[4][4] = {};
  for (int k0 = 0; k0 < K; k0 += 16) {
    __syncthreads();
    f32x4 zv = *(const f32x4*)(Z + (size_t)(b0 + lr) * K + k0 + lc);
    f32x4 wv = {0.f, 0.f, 0.f, 0.f};
    if (n0 + lr < N) wv = *(const f32x4*)(W + (size_t)(n0 + lr) * K + k0 + lc);
    Zt[lr][lc + 0] = zv.x; Zt[lr][lc + 1] = zv.y; Zt[lr][lc + 2] = zv.z; Zt[lr][lc + 3] = zv.w;
    Wt[lr][lc + 0] = wv.x; Wt[lr][lc + 1] = wv.y; Wt[lr][lc + 2] = wv.z; Wt[lr][lc + 3] = wv.w;
    __syncthreads();
#pragma unroll
    for (int kk = 0; kk < 16; kk++) {
      float av[4], bw[4];
#pragma unroll
      for (int i = 0; i < 4; i++) av[i] = Zt[ty * 4 + i][kk];
#pragma unroll
      for (int i = 0; i < 4; i++) bw[i] = Wt[tx * 4 + i][kk];
#pragma unroll
      for (int i = 0; i < 4; i++)
#pragma unroll
        for (int jj = 0; jj < 4; jj++) acc[i][jj] += av[i] * bw[jj];
    }
  }
#pragma unroll
  for (int i = 0; i < 4; i++)
#pragma unroll
    for (int jj = 0; jj < 4; jj++) {
      int bb = b0 + ty * 4 + i;
      int n = n0 + tx * 4 + jj;
      if (n < N) {
        float v = acc[i][jj] + bias[n];
        out[(size_t)bb * N + n] = (ACT == 0) ? fmaxf(v, 0.f) : 1.f / (1.f + __expf(-v));
      }
    }
}

extern "C" void kernel_launch(void* const* d_in, const int* in_sizes, int n_in,
                              void* d_out, int out_size, void* d_ws, size_t ws_size,
                              hipStream_t stream) {
  const float* x       = (const float*)d_in[0];
  const int* targets   = (const int*)d_in[1];
  const float* Wc      = (const float*)d_in[2];
  const float* bc      = (const float*)d_in[3];
  const float* Wp      = (const float*)d_in[4];
  const float* bp      = (const float*)d_in[5];
  const float* Wd      = (const float*)d_in[6];
  const float* W1      = (const float*)d_in[7];
  const float* b1      = (const float*)d_in[8];
  const float* W2      = (const float*)d_in[9];
  const float* b2      = (const float*)d_in[10];
  const float* W3      = (const float*)d_in[11];
  const float* b3      = (const float*)d_in[12];

  char* ws = (char*)d_ws;
  const size_t MB = 1024 * 1024;
  // Conv phase (quarters of 128 imgs):
  //   wTr32 [0, 20.25)   fp32 [t][n][ci] weights
  //   h64   [21, 111.25) 19x19x256 f64 per image (one quarter)
  //   u64   [112, 148)   conv2 out full batch -> squashed in place
  // Peak 148 MiB (proven-safe; R11 used 213).
  float* wTr32 = (float*)ws;
  double* h64  = (double*)(ws + 21 * MB);
  double* u64  = (double*)(ws + 112 * MB);
  // Routing phase (wTr/h dead): all below 112 MiB.
  double* uhat64 = (double*)(ws);             // 90   [0,90)
  double* bij64  = (double*)(ws + 90 * MB);   // 5.63 [90,96)
  double* cij64  = (double*)(ws + 96 * MB);   // 5.63 [96,102)
  double* sj64   = (double*)(ws + 102 * MB);  // 0.08
  float* z1      = (float*)(ws + 103 * MB);   // 1 MiB
  float* z2      = (float*)(ws + 104 * MB);   // 2 MiB

  float* vout   = (float*)d_out;                  // [512,10,16]
  float* recon  = (float*)d_out + 81920;          // [512,784]
  float* idxout = (float*)d_out + 81920 + 401408; // [512]

  k_w64t<<<20736, 256, 0, stream>>>(Wp, wTr32);
  for (int q = 0; q < 4; q++) {
    k_conv1_19<<<256, 256, 0, stream>>>(x + (size_t)q * 128 * 784, Wc, bc, h64);
    k_conv2_v<<<1024, 64, 0, stream>>>(h64, wTr32, u64, q * 128);
  }
  k_squash_ip<<<2304, 256, 0, stream>>>(u64, bp);
  for (int e = 0; e < 8; e++) {
    int b0 = e * 64;
    k_uhat64<<<1152, 320, 0, stream>>>(u64, Wd, uhat64, b0);
    k_route_s<0><<<dim3(64, 10), 256, 0, stream>>>(uhat64, cij64, sj64);
    k_route_b<true><<<dim3(64, 9), 256, 0, stream>>>(uhat64, sj64, bij64);
    k_cij<<<dim3(64, 6), 192, 0, stream>>>(bij64, cij64);
    k_route_s<1><<<dim3(64, 10), 256, 0, stream>>>(uhat64, cij64, sj64);
    k_route_b<false><<<dim3(64, 9), 256, 0, stream>>>(uhat64, sj64, bij64);
    k_cij<<<dim3(64, 6), 192, 0, stream>>>(bij64, cij64);
    k_route_s<2><<<dim3(64, 10), 256, 0, stream>>>(uhat64, cij64, sj64);
    k_epi<<<64, 192, 0, stream>>>(sj64, vout, idxout, b0);
  }
  k_z1<<<1024, 256, 0, stream>>>(vout, targets, W1, b1, z1);
  k_gemm_act<0><<<dim3(8, 16), 256, 0, stream>>>(z1, W2, b2, z2, 1024, 512);
  k_gemm_act<1><<<dim3(8, 13), 256, 0, stream>>>(z2, W3, b3, recon, 784, 1024);
}

// Round 4
// 25298.874 us; speedup vs baseline: 2.3496x; 2.3496x over previous
//
#include <hip/hip_runtime.h>
#include <math.h>

typedef __attribute__((ext_vector_type(2))) double f64x2;
typedef __attribute__((ext_vector_type(4))) float f32x4;

// ---------------- Wp -> wT fp64, layout [k][n], k=(ky*9+kx)*256+ci --------------
// (double)f32 is exact -> conv2 products bit-identical to the passing chain.
__global__ __launch_bounds__(256) void k_w64kn(const float* __restrict__ Wp,
                                               double* __restrict__ wT) {
  int gid = blockIdx.x * 256 + threadIdx.x;  // 20736*256
  int n = gid & 255, k = gid >> 8;
  int t = k >> 8, ci = k & 255;
  wT[gid] = (double)Wp[(size_t)n * 20736 + ci * 81 + t];
}

// ---------------- Conv1: 1->256 k9 s1, fp64, out [img][y][x][256], 19x19 --------
// (chunk-local img indexing; bit-same values as the R3-passing kernel)
__global__ __launch_bounds__(256) void k_conv1_19(const float* __restrict__ x,
                                                  const float* __restrict__ Wc,
                                                  const float* __restrict__ bc,
                                                  double* __restrict__ h) {
  int b = blockIdx.x >> 1;
  int rh = (blockIdx.x & 1) * 10;
  int re = rh ? 19 : 10;
  int oc = threadIdx.x;
  __shared__ float xs[784];
  for (int i = threadIdx.x; i < 784; i += 256) xs[i] = x[(size_t)b * 784 + i];
  __syncthreads();
  float w[81];
#pragma unroll
  for (int t = 0; t < 81; t++) w[t] = Wc[(size_t)oc * 81 + t];
  double bias = (double)bc[oc];
  for (int oh = rh; oh < re; oh++) {
    for (int ow4 = 0; ow4 < 20; ow4 += 4) {
      double a0 = bias, a1 = bias, a2 = bias, a3 = bias;
#pragma unroll
      for (int ky = 0; ky < 9; ky++) {
        const float* xr = &xs[(oh + ky) * 28 + ow4];
#pragma unroll
        for (int kx = 0; kx < 9; kx++) {
          double wv = (double)w[ky * 9 + kx];
          a0 += wv * (double)xr[kx + 0];
          a1 += wv * (double)xr[kx + 1];
          a2 += wv * (double)xr[kx + 2];
          a3 += wv * (double)xr[kx + 3];
        }
      }
      size_t base = ((size_t)(b * 19 + oh) * 19 + ow4) * 256 + oc;
      h[base + 0]   = fmax(a0, 0.0);
      h[base + 256] = fmax(a1, 0.0);
      h[base + 512] = fmax(a2, 0.0);
      if (ow4 < 16) h[base + 768] = fmax(a3, 0.0);  // skip col 19
    }
  }
}

// ---------------- Conv2: LDS-A + register-ring-B fp64 GEMM ----------------------
// One launch covers 6144 m-rows (96 m-tiles x 8 n-tiles = 768 blocks of 4 waves
// = exactly 3 blocks/CU, 3 waves/SIMD). Wave tile 64m x 8n: lane <-> m, acc[8].
// A staged [kk][m] in LDS (1 ds_read_b64 per kk); B = wave-uniform VMEM f64x2
// ring (depth 4, prefetch distance 4 k's). Per-output accumulation is the exact
// k-ascending sequential fma chain (k = (ky*9+kx)*256+ci) -> bit-identical.
__global__ __launch_bounds__(256, 3) void k_conv2_s(const double* __restrict__ h,
                                                    const double* __restrict__ wT,
                                                    double* __restrict__ uraw,
                                                    int mG0, int imgLo) {
  __shared__ double As[32][64];
  int tid = threadIdx.x;
  int mt = blockIdx.x >> 3, ntb = blockIdx.x & 7;
  int lane = tid & 63;
  int wv = tid >> 6;
  int n0 = ntb * 32 + wv * 8;
  int mG = mG0 + mt * 64 + lane;
  int img = mG / 36, sp = mG % 36;
  size_t sbase = ((size_t)((img - imgLo) * 361 + (sp / 6) * 38 + (sp % 6) * 2)) * 256;
  const double* hrow = h + sbase;

  double acc[8];
#pragma unroll
  for (int e = 0; e < 8; e++) acc[e] = 0.0;

  // B ring: slot s holds B[k][n0..n0+8) for the next k with k%4==s
  f64x2 bring[4][4];
  {
    const double* b0 = wT + n0;
#pragma unroll
    for (int s = 0; s < 4; s++)
#pragma unroll
      for (int j = 0; j < 4; j++) bring[s][j] = *(const f64x2*)(b0 + s * 256 + 2 * j);
  }
  const double* bpre = wT + 4 * 256 + n0;

  // A prefetch for ks=0 (tap 0, ci0=0)
  f64x2 pa[4];
  {
    const double* ga = hrow + wv * 8;
#pragma unroll
    for (int j = 0; j < 4; j++) pa[j] = *(const f64x2*)(ga + 2 * j);
  }

  for (int ks = 0; ks < 648; ks++) {
    __syncthreads();
#pragma unroll
    for (int j = 0; j < 4; j++) {
      As[wv * 8 + 2 * j + 0][lane] = pa[j].x;
      As[wv * 8 + 2 * j + 1][lane] = pa[j].y;
    }
    __syncthreads();
    if (ks + 1 < 648) {
      int t = (ks + 1) >> 3, ci0 = ((ks + 1) & 7) * 32;
      const double* ga = hrow + (size_t)((t / 9) * 19 + (t % 9)) * 256 + ci0 + wv * 8;
#pragma unroll
      for (int j = 0; j < 4; j++) pa[j] = *(const f64x2*)(ga + 2 * j);
    }
#pragma unroll
    for (int kk = 0; kk < 32; kk++) {
      double a = As[kk][lane];
      const int s = kk & 3;
      acc[0] = fma(a, bring[s][0].x, acc[0]);
      acc[1] = fma(a, bring[s][0].y, acc[1]);
      acc[2] = fma(a, bring[s][1].x, acc[2]);
      acc[3] = fma(a, bring[s][1].y, acc[3]);
      acc[4] = fma(a, bring[s][2].x, acc[4]);
      acc[5] = fma(a, bring[s][2].y, acc[5]);
      acc[6] = fma(a, bring[s][3].x, acc[6]);
      acc[7] = fma(a, bring[s][3].y, acc[7]);
      // refill slot s for k+4 (reads past 20736 hit the pad rows; never consumed)
#pragma unroll
      for (int j = 0; j < 4; j++) bring[s][j] = *(const f64x2*)(bpre + 2 * j);
      bpre += 256;
    }
  }
  // out[b][ch][sp]: capsule features = 8 consecutive doubles
  size_t ob = (size_t)img * 9216 + sp;
#pragma unroll
  for (int e = 0; e < 8; e++) uraw[ob + (size_t)(n0 + e) * 36] = acc[e];
}

// ---------------- squash of primary capsules, fp64, IN PLACE --------------------
__global__ __launch_bounds__(256) void k_squash_ip(double* __restrict__ u,
                                                   const float* __restrict__ bp) {
  int idx = blockIdx.x * 256 + threadIdx.x;  // (b,c): 512*1152
  int bl = idx / 1152, c = idx % 1152;
  size_t base = ((size_t)bl * 1152 + c) * 8;
  double v[8];
  double ns = 0.0;
#pragma unroll
  for (int i = 0; i < 8; i++) {
    int f = c * 8 + i;
    int ch = f / 36;
    double val = u[base + i] + (double)bp[ch];
    v[i] = val;
    ns += val * val;
  }
  double sc = (ns / (1.0 + ns)) / (0.001 + sqrt(ns));
#pragma unroll
  for (int i = 0; i < 8; i++) u[base + i] = v[i] * sc;
}

// ---------------- u_hat fp64, eighth batch (bl in [0,64)) -----------------------
__global__ __launch_bounds__(320) void k_uhat64(const double* __restrict__ u,
                                                const float* __restrict__ Wd,
                                                double* __restrict__ uhat, int b0) {
  int c = blockIdx.x;
  int t = threadIdx.x;
  int jo = t % 160, half = t / 160;
  double w[8];
#pragma unroll
  for (int i = 0; i < 8; i++) w[i] = (double)Wd[((size_t)c * 160 + jo) * 8 + i];
  for (int it = 0; it < 32; it++) {
    int bl = it * 2 + half;
    const double* up = u + ((size_t)(b0 + bl) * 1152 + c) * 8;
    double s = 0.0;
#pragma unroll
    for (int i = 0; i < 8; i++) s += w[i] * up[i];
    uhat[((size_t)bl * 1152 + c) * 160 + jo] = s;
  }
}

// ---------------- c_ij = softmax(b_ij) fp64, wide grid --------------------------
__global__ __launch_bounds__(192) void k_cij(const double* __restrict__ bij,
                                             double* __restrict__ cij) {
  int bl = blockIdx.x;
  int c = blockIdx.y * 192 + threadIdx.x;  // 6*192 = 1152
  const double* bp_ = bij + ((size_t)bl * 1152 + c) * 10;
  double bv[10], mx = -1e300;
#pragma unroll
  for (int j = 0; j < 10; j++) { bv[j] = bp_[j]; mx = fmax(mx, bv[j]); }
  double s = 0.0;
#pragma unroll
  for (int j = 0; j < 10; j++) { bv[j] = exp(bv[j] - mx); s += bv[j]; }
  double inv = 1.0 / s;
  double* cp = cij + ((size_t)bl * 1152 + c) * 10;
#pragma unroll
  for (int j = 0; j < 10; j++) cp[j] = bv[j] * inv;
}

// ---------------- routing s_j pass fp64, wide coalesced grid (bl x j) -----------
template <int IT>
__global__ __launch_bounds__(256) void k_route_s(const double* __restrict__ uhat,
                                                 const double* __restrict__ cij,
                                                 double* __restrict__ sj) {
  int bl = blockIdx.x, j = blockIdx.y;
  int tid = threadIdx.x;
  int o = tid & 15, cl = tid >> 4;
  double acc = 0.0;
  const double* up = uhat + (size_t)bl * 1152 * 160 + j * 16 + o;
  if (IT == 0) {
    for (int c = cl; c < 1152; c += 16) acc += 0.1 * up[(size_t)c * 160];
  } else {
    const double* cp = cij + (size_t)bl * 1152 * 10 + j;
    for (int c = cl; c < 1152; c += 16) acc += cp[(size_t)c * 10] * up[(size_t)c * 160];
  }
  __shared__ double red[256];
  red[tid] = acc;
  __syncthreads();
#pragma unroll
  for (int s = 128; s >= 16; s >>= 1) {
    if (tid < s) red[tid] += red[tid + s];
    __syncthreads();
  }
  if (tid < 16) sj[(size_t)bl * 160 + j * 16 + tid] = red[tid];
}

// ---------------- agreement update b_ij fp64, wide grid -------------------------
template <bool FIRST>
__global__ __launch_bounds__(256) void k_route_b(const double* __restrict__ uhat,
                                                 const double* __restrict__ sj,
                                                 double* __restrict__ bij) {
  __shared__ double sl[160];
  int bl = blockIdx.x;
  int tid = threadIdx.x;
  if (tid < 160) sl[tid] = sj[(size_t)bl * 160 + tid];
  __syncthreads();
  int c = blockIdx.y * 128 + (tid >> 1);
  int j0 = (tid & 1) * 5;
  const double* up = uhat + ((size_t)bl * 1152 + c) * 160;
  double* bp_ = bij + ((size_t)bl * 1152 + c) * 10;
#pragma unroll
  for (int jj = 0; jj < 5; jj++) {
    int j = j0 + jj;
    double dot = 0.0;
#pragma unroll
    for (int oo = 0; oo < 16; oo++) dot += sl[j * 16 + oo] * up[j * 16 + oo];
    bp_[j] = (FIRST ? 0.0 : bp_[j]) + dot;
  }
}

// ---------------- epilogue: np-fp32-canonical (verbatim passing chain) ----------
__global__ __launch_bounds__(192) void k_epi(const double* __restrict__ sj,
                                             float* __restrict__ vout,
                                             float* __restrict__ idxout, int b0) {
#pragma clang fp contract(off)
  __shared__ float vsh[160];
  __shared__ float len32[10];
  int bl = blockIdx.x;
  int tid = threadIdx.x;
  const double* sp = sj + (size_t)bl * 160;
  if (tid < 10) {
    float s32[16], a[16];
#pragma unroll
    for (int o = 0; o < 16; o++) { s32[o] = (float)sp[tid * 16 + o]; a[o] = s32[o] * s32[o]; }
    float r[8];
#pragma unroll
    for (int k = 0; k < 8; k++) r[k] = a[k] + a[k + 8];
    float ns = ((r[0] + r[1]) + (r[2] + r[3])) + ((r[4] + r[5]) + (r[6] + r[7]));
    float A = ns / (1.0f + ns);
    float D = 0.001f + sqrtf(ns);
#pragma unroll
    for (int o = 0; o < 16; o++) {
      float v = A * (s32[o] / D);
      vsh[tid * 16 + o] = v;
      a[o] = v * v;
    }
#pragma unroll
    for (int k = 0; k < 8; k++) r[k] = a[k] + a[k + 8];
    float nv = ((r[0] + r[1]) + (r[2] + r[3])) + ((r[4] + r[5]) + (r[6] + r[7]));
    len32[tid] = sqrtf(nv);
  }
  __syncthreads();
  if (tid < 160) vout[(size_t)(b0 + bl) * 160 + tid] = vsh[tid];
  if (tid == 0) {
    float mx = len32[0];
    for (int jj = 1; jj < 10; jj++) mx = fmaxf(mx, len32[jj]);
    float e[10];
    for (int jj = 0; jj < 10; jj++) e[jj] = (float)exp((double)(len32[jj] - mx));
    float ssum = ((e[0] + e[1]) + (e[2] + e[3])) + ((e[4] + e[5]) + (e[6] + e[7]));
    ssum = ssum + e[8];
    ssum = ssum + e[9];
    int best = 0;
    float bst = e[0] / ssum;
    for (int jj = 1; jj < 10; jj++) {
      float p = e[jj] / ssum;
      if (p > bst) { bst = p; best = jj; }
    }
    idxout[b0 + bl] = (float)best;
  }
}

// ---------------- decoder layer 1 (masked input has only 16 nonzeros) -----------
__global__ __launch_bounds__(256) void k_z1(const float* __restrict__ vout,
                                            const int* __restrict__ targets,
                                            const float* __restrict__ W1,
                                            const float* __restrict__ b1,
                                            float* __restrict__ z1) {
  int id = blockIdx.x * 256 + threadIdx.x;
  int b = id >> 9, n = id & 511;
  int t = targets[b];
  float acc = b1[n];
  const float* wr = W1 + (size_t)n * 160 + t * 16;
  const float* vr = vout + (size_t)b * 160 + t * 16;
#pragma unroll
  for (int o = 0; o < 16; o++) acc += wr[o] * vr[o];
  z1[id] = fmaxf(acc, 0.f);
}

// ---------------- generic fp32 GEMM: out[b,n] = act(Z[b,:]·W[n,:] + bias[n]) ----
template <int ACT>
__global__ __launch_bounds__(256) void k_gemm_act(const float* __restrict__ Z,
                                                  const float* __restrict__ W,
                                                  const float* __restrict__ bias,
                                                  float* __restrict__ out, int N, int K) {
  __shared__ float Zt[64][17];
  __shared__ float Wt[64][17];
  int b0 = blockIdx.x * 64;
  int n0 = blockIdx.y * 64;
  int tid = threadIdx.x;
  int ty = tid >> 4, tx = tid & 15;
  int lr = tid >> 2, lc = (tid & 3) * 4;
  float acc[4][4] = {};
  for (int k0 = 0; k0 < K; k0 += 16) {
    __syncthreads();
    f32x4 zv = *(const f32x4*)(Z + (size_t)(b0 + lr) * K + k0 + lc);
    f32x4 wv = {0.f, 0.f, 0.f, 0.f};
    if (n0 + lr < N) wv = *(const f32x4*)(W + (size_t)(n0 + lr) * K + k0 + lc);
    Zt[lr][lc + 0] = zv.x; Zt[lr][lc + 1] = zv.y; Zt[lr][lc + 2] = zv.z; Zt[lr][lc + 3] = zv.w;
    Wt[lr][lc + 0] = wv.x; Wt[lr][lc + 1] = wv.y; Wt[lr][lc + 2] = wv.z; Wt[lr][lc + 3] = wv.w;
    __syncthreads();
#pragma unroll
    for (int kk = 0; kk < 16; kk++) {
      float av[4], bw[4];
#pragma unroll
      for (int i = 0; i < 4; i++) av[i] = Zt[ty * 4 + i][kk];
#pragma unroll
      for (int i = 0; i < 4; i++) bw[i] = Wt[tx * 4 + i][kk];
#pragma unroll
      for (int i = 0; i < 4; i++)
#pragma unroll
        for (int jj = 0; jj < 4; jj++) acc[i][jj] += av[i] * bw[jj];
    }
  }
#pragma unroll
  for (int i = 0; i < 4; i++)
#pragma unroll
    for (int jj = 0; jj < 4; jj++) {
      int bb = b0 + ty * 4 + i;
      int n = n0 + tx * 4 + jj;
      if (n < N) {
        float v = acc[i][jj] + bias[n];
        out[(size_t)bb * N + n] = (ACT == 0) ? fmaxf(v, 0.f) : 1.f / (1.f + __expf(-v));
      }
    }
}

extern "C" void kernel_launch(void* const* d_in, const int* in_sizes, int n_in,
                              void* d_out, int out_size, void* d_ws, size_t ws_size,
                              hipStream_t stream) {
  const float* x       = (const float*)d_in[0];
  const int* targets   = (const int*)d_in[1];
  const float* Wc      = (const float*)d_in[2];
  const float* bc      = (const float*)d_in[3];
  const float* Wp      = (const float*)d_in[4];
  const float* bp      = (const float*)d_in[5];
  const float* Wd      = (const float*)d_in[6];
  const float* W1      = (const float*)d_in[7];
  const float* b1      = (const float*)d_in[8];
  const float* W2      = (const float*)d_in[9];
  const float* b2      = (const float*)d_in[10];
  const float* W3      = (const float*)d_in[11];
  const float* b3      = (const float*)d_in[12];

  char* ws = (char*)d_ws;
  const size_t MB = 1024 * 1024;
  // Conv phase (3 chunks of <=172 imgs):
  //   wT64 [0, 41)     fp64 [k][n] weights (+pad rows for B-ring overfetch)
  //   h64  [41, 169)   19x19x256 f64 per image, chunk-local
  //   u64  [169, 205)  conv2 out full batch -> squashed in place
  // Peak 205 MiB (proven-safe envelope: 213).
  double* wT64 = (double*)ws;
  double* h64  = (double*)(ws + 41 * MB);
  double* u64  = (double*)(ws + 169 * MB);
  // Routing phase (wT64/h64 dead): all below 169 MiB.
  double* uhat64 = (double*)(ws);             // 90   [0,90)
  double* bij64  = (double*)(ws + 90 * MB);   // 5.63 [90,96)
  double* cij64  = (double*)(ws + 96 * MB);   // 5.63 [96,102)
  double* sj64   = (double*)(ws + 102 * MB);  // 0.08
  float* z1      = (float*)(ws + 103 * MB);   // 1 MiB
  float* z2      = (float*)(ws + 104 * MB);   // 2 MiB

  float* vout   = (float*)d_out;                  // [512,10,16]
  float* recon  = (float*)d_out + 81920;          // [512,784]
  float* idxout = (float*)d_out + 81920 + 401408; // [512]

  k_w64kn<<<20736, 256, 0, stream>>>(Wp, wT64);
  const int iLo[3] = {0, 170, 341};
  const int iHi[3] = {171, 342, 512};
  for (int L = 0; L < 3; L++) {
    int cnt = iHi[L] - iLo[L];
    k_conv1_19<<<cnt * 2, 256, 0, stream>>>(x + (size_t)iLo[L] * 784, Wc, bc, h64);
    k_conv2_s<<<768, 256, 0, stream>>>(h64, wT64, u64, 6144 * L, iLo[L]);
  }
  k_squash_ip<<<2304, 256, 0, stream>>>(u64, bp);
  for (int e = 0; e < 8; e++) {
    int b0 = e * 64;
    k_uhat64<<<1152, 320, 0, stream>>>(u64, Wd, uhat64, b0);
    k_route_s<0><<<dim3(64, 10), 256, 0, stream>>>(uhat64, cij64, sj64);
    k_route_b<true><<<dim3(64, 9), 256, 0, stream>>>(uhat64, sj64, bij64);
    k_cij<<<dim3(64, 6), 192, 0, stream>>>(bij64, cij64);
    k_route_s<1><<<dim3(64, 10), 256, 0, stream>>>(uhat64, cij64, sj64);
    k_route_b<false><<<dim3(64, 9), 256, 0, stream>>>(uhat64, sj64, bij64);
    k_cij<<<dim3(64, 6), 192, 0, stream>>>(bij64, cij64);
    k_route_s<2><<<dim3(64, 10), 256, 0, stream>>>(uhat64, cij64, sj64);
    k_epi<<<64, 192, 0, stream>>>(sj64, vout, idxout, b0);
  }
  k_z1<<<1024, 256, 0, stream>>>(vout, targets, W1, b1, z1);
  k_gemm_act<0><<<dim3(8, 16), 256, 0, stream>>>(z1, W2, b2, z2, 1024, 512);
  k_gemm_act<1><<<dim3(8, 13), 256, 0, stream>>>(z2, W3, b3, recon, 784, 1024);
}

// Round 5
// 11491.698 us; speedup vs baseline: 5.1726x; 2.2015x over previous
//
#include <hip/hip_runtime.h>
#include <math.h>

typedef __attribute__((ext_vector_type(2))) double f64x2;
typedef __attribute__((ext_vector_type(2))) float f32x2;
typedef __attribute__((ext_vector_type(4))) float f32x4;

// ---------------- Wp -> wT fp32, layout [k][n], k=(ky*9+kx)*256+ci --------------
// Values are raw fp32 Wp entries; (double)f32 at use is exact -> products
// bit-identical to the proven fp64 chain.
__global__ __launch_bounds__(256) void k_wkn(const float* __restrict__ Wp,
                                             float* __restrict__ wT) {
  const int total = 20736 * 256;
  for (int gid = blockIdx.x * 256 + threadIdx.x; gid < total; gid += gridDim.x * 256) {
    int k = gid >> 8, n = gid & 255;
    int t = k >> 8, ci = k & 255;
    wT[gid] = Wp[(size_t)n * 20736 + ci * 81 + t];
  }
}

// ---------------- Conv1: 1->256 k9 s1, fp64, out [img][y][x][256], 19x19 --------
__global__ __launch_bounds__(256) void k_conv1_19(const float* __restrict__ x,
                                                  const float* __restrict__ Wc,
                                                  const float* __restrict__ bc,
                                                  double* __restrict__ h) {
  int b = blockIdx.x >> 1;
  int rh = (blockIdx.x & 1) * 10;
  int re = rh ? 19 : 10;
  int oc = threadIdx.x;
  __shared__ float xs[784];
  for (int i = threadIdx.x; i < 784; i += 256) xs[i] = x[(size_t)b * 784 + i];
  __syncthreads();
  float w[81];
#pragma unroll
  for (int t = 0; t < 81; t++) w[t] = Wc[(size_t)oc * 81 + t];
  double bias = (double)bc[oc];
  for (int oh = rh; oh < re; oh++) {
    for (int ow4 = 0; ow4 < 20; ow4 += 4) {
      double a0 = bias, a1 = bias, a2 = bias, a3 = bias;
#pragma unroll
      for (int ky = 0; ky < 9; ky++) {
        const float* xr = &xs[(oh + ky) * 28 + ow4];
#pragma unroll
        for (int kx = 0; kx < 9; kx++) {
          double wv = (double)w[ky * 9 + kx];
          a0 += wv * (double)xr[kx + 0];
          a1 += wv * (double)xr[kx + 1];
          a2 += wv * (double)xr[kx + 2];
          a3 += wv * (double)xr[kx + 3];
        }
      }
      size_t base = ((size_t)(b * 19 + oh) * 19 + ow4) * 256 + oc;
      h[base + 0]   = fmax(a0, 0.0);
      h[base + 256] = fmax(a1, 0.0);
      h[base + 512] = fmax(a2, 0.0);
      if (ow4 < 16) h[base + 768] = fmax(a3, 0.0);  // skip col 19
    }
  }
}

// ---------------- Conv2 implicit GEMM, fp64 VALU, LDS-staged A and B ------------
// 64x64 tile, 512 threads (8 waves), thread tile 2m x 4n, BK=16.
// Per-output accumulation: k = (ky*9+kx)*256+ci ASCENDING, one sequential fma
// per k -> bit-identical to the proven chain. B staged from fp32 [k][n] with
// bank-spreading column map colp(n) = n + 2*(n>>4) (b128 reads 2-way = free).
__global__ __launch_bounds__(512, 4) void k_conv2_t(const double* __restrict__ h,
                                                    const float* __restrict__ wT,
                                                    double* __restrict__ uraw,
                                                    int mG0, int imgLo) {
  __shared__ __align__(16) double AsT[16][66];  // [k][m]
  __shared__ __align__(16) double BsT[16][72];  // [k][colp(n)]
  int tid = threadIdx.x;
  int m0 = blockIdx.x * 64, n0 = blockIdx.y * 64;

  // A staging: 64 m x 16 k / 512 thr -> 1 f64x2 (2 k's) per thread
  int sm = tid >> 3, skA = (tid & 7) * 2;
  int mGa = mG0 + m0 + sm;
  int imga = mGa / 36, spa = mGa % 36;
  size_t abase = ((size_t)((imga - imgLo) * 361 + (spa / 6) * 38 + (spa % 6) * 2)) * 256;
  // B staging: 16 k x 64 n f32 / 512 thr -> 1 f32x2 (2 n's) per thread
  int kb = tid >> 5, nb2 = (tid & 31) * 2;
  int colB = nb2 + 2 * (nb2 >> 4);
  // compute coords
  int ty = tid >> 4, tx = tid & 15;   // ty 0..31 (2 m's), tx 0..15 (4 n's)
  int colp = tx * 4 + 2 * (tx >> 2);

  double acc[2][4];
#pragma unroll
  for (int i = 0; i < 2; i++)
#pragma unroll
    for (int j = 0; j < 4; j++) acc[i][j] = 0.0;

  auto gk = [](int k) -> size_t {
    int t = k >> 8, ci = k & 255;
    return (size_t)((t / 9) * 19 + (t % 9)) * 256 + ci;
  };

  f64x2 pa = *(const f64x2*)(h + abase + gk(skA));
  f32x2 pb = *(const f32x2*)(wT + (size_t)kb * 256 + n0 + nb2);

  for (int ks = 0; ks < 1296; ks++) {
    __syncthreads();
    AsT[skA + 0][sm] = pa.x;
    AsT[skA + 1][sm] = pa.y;
    *(f64x2*)&BsT[kb][colB] = f64x2{(double)pb.x, (double)pb.y};
    __syncthreads();
    if (ks + 1 < 1296) {
      int k0 = (ks + 1) * 16;
      pa = *(const f64x2*)(h + abase + gk(k0 + skA));
      pb = *(const f32x2*)(wT + (size_t)(k0 + kb) * 256 + n0 + nb2);
    }
#pragma unroll
    for (int kk = 0; kk < 16; kk++) {
      f64x2 av  = *(const f64x2*)&AsT[kk][ty * 2];
      f64x2 b01 = *(const f64x2*)&BsT[kk][colp];
      f64x2 b23 = *(const f64x2*)&BsT[kk][colp + 2];
      acc[0][0] = fma(av.x, b01.x, acc[0][0]);
      acc[0][1] = fma(av.x, b01.y, acc[0][1]);
      acc[0][2] = fma(av.x, b23.x, acc[0][2]);
      acc[0][3] = fma(av.x, b23.y, acc[0][3]);
      acc[1][0] = fma(av.y, b01.x, acc[1][0]);
      acc[1][1] = fma(av.y, b01.y, acc[1][1]);
      acc[1][2] = fma(av.y, b23.x, acc[1][2]);
      acc[1][3] = fma(av.y, b23.y, acc[1][3]);
    }
  }

  // out[b][ch][sp]: capsule features = 8 consecutive doubles (ch*36+sp = cap*8+feat)
#pragma unroll
  for (int i = 0; i < 2; i++) {
    int mG = mG0 + m0 + ty * 2 + i;
    int img = mG / 36, sp = mG % 36;
    size_t ob = (size_t)img * 9216 + sp;
#pragma unroll
    for (int j = 0; j < 4; j++) {
      int n = n0 + tx * 4 + j;
      uraw[ob + (size_t)n * 36] = acc[i][j];
    }
  }
}

// ---------------- squash of primary capsules, fp64, IN PLACE --------------------
__global__ __launch_bounds__(256) void k_squash_ip(double* __restrict__ u,
                                                   const float* __restrict__ bp) {
  int idx = blockIdx.x * 256 + threadIdx.x;  // (b,c): 512*1152
  int bl = idx / 1152, c = idx % 1152;
  size_t base = ((size_t)bl * 1152 + c) * 8;
  double v[8];
  double ns = 0.0;
#pragma unroll
  for (int i = 0; i < 8; i++) {
    int f = c * 8 + i;
    int ch = f / 36;
    double val = u[base + i] + (double)bp[ch];
    v[i] = val;
    ns += val * val;
  }
  double sc = (ns / (1.0 + ns)) / (0.001 + sqrt(ns));
#pragma unroll
  for (int i = 0; i < 8; i++) u[base + i] = v[i] * sc;
}

// ---------------- u_hat fp64, eighth batch (bl in [0,64)) -----------------------
__global__ __launch_bounds__(320) void k_uhat64(const double* __restrict__ u,
                                                const float* __restrict__ Wd,
                                                double* __restrict__ uhat, int b0) {
  int c = blockIdx.x;
  int t = threadIdx.x;
  int jo = t % 160, half = t / 160;
  double w[8];
#pragma unroll
  for (int i = 0; i < 8; i++) w[i] = (double)Wd[((size_t)c * 160 + jo) * 8 + i];
  for (int it = 0; it < 32; it++) {
    int bl = it * 2 + half;
    const double* up = u + ((size_t)(b0 + bl) * 1152 + c) * 8;
    double s = 0.0;
#pragma unroll
    for (int i = 0; i < 8; i++) s += w[i] * up[i];
    uhat[((size_t)bl * 1152 + c) * 160 + jo] = s;
  }
}

// ---------------- c_ij = softmax(b_ij) fp64, wide grid --------------------------
__global__ __launch_bounds__(192) void k_cij(const double* __restrict__ bij,
                                             double* __restrict__ cij) {
  int bl = blockIdx.x;
  int c = blockIdx.y * 192 + threadIdx.x;  // 6*192 = 1152
  const double* bp_ = bij + ((size_t)bl * 1152 + c) * 10;
  double bv[10], mx = -1e300;
#pragma unroll
  for (int j = 0; j < 10; j++) { bv[j] = bp_[j]; mx = fmax(mx, bv[j]); }
  double s = 0.0;
#pragma unroll
  for (int j = 0; j < 10; j++) { bv[j] = exp(bv[j] - mx); s += bv[j]; }
  double inv = 1.0 / s;
  double* cp = cij + ((size_t)bl * 1152 + c) * 10;
#pragma unroll
  for (int j = 0; j < 10; j++) cp[j] = bv[j] * inv;
}

// ---------------- routing s_j pass fp64, wide coalesced grid (bl x j) -----------
template <int IT>
__global__ __launch_bounds__(256) void k_route_s(const double* __restrict__ uhat,
                                                 const double* __restrict__ cij,
                                                 double* __restrict__ sj) {
  int bl = blockIdx.x, j = blockIdx.y;
  int tid = threadIdx.x;
  int o = tid & 15, cl = tid >> 4;
  double acc = 0.0;
  const double* up = uhat + (size_t)bl * 1152 * 160 + j * 16 + o;
  if (IT == 0) {
    for (int c = cl; c < 1152; c += 16) acc += 0.1 * up[(size_t)c * 160];
  } else {
    const double* cp = cij + (size_t)bl * 1152 * 10 + j;
    for (int c = cl; c < 1152; c += 16) acc += cp[(size_t)c * 10] * up[(size_t)c * 160];
  }
  __shared__ double red[256];
  red[tid] = acc;
  __syncthreads();
#pragma unroll
  for (int s = 128; s >= 16; s >>= 1) {
    if (tid < s) red[tid] += red[tid + s];
    __syncthreads();
  }
  if (tid < 16) sj[(size_t)bl * 160 + j * 16 + tid] = red[tid];
}

// ---------------- agreement update b_ij fp64, wide grid -------------------------
template <bool FIRST>
__global__ __launch_bounds__(256) void k_route_b(const double* __restrict__ uhat,
                                                 const double* __restrict__ sj,
                                                 double* __restrict__ bij) {
  __shared__ double sl[160];
  int bl = blockIdx.x;
  int tid = threadIdx.x;
  if (tid < 160) sl[tid] = sj[(size_t)bl * 160 + tid];
  __syncthreads();
  int c = blockIdx.y * 128 + (tid >> 1);
  int j0 = (tid & 1) * 5;
  const double* up = uhat + ((size_t)bl * 1152 + c) * 160;
  double* bp_ = bij + ((size_t)bl * 1152 + c) * 10;
#pragma unroll
  for (int jj = 0; jj < 5; jj++) {
    int j = j0 + jj;
    double dot = 0.0;
#pragma unroll
    for (int oo = 0; oo < 16; oo++) dot += sl[j * 16 + oo] * up[j * 16 + oo];
    bp_[j] = (FIRST ? 0.0 : bp_[j]) + dot;
  }
}

// ---------------- epilogue: np-fp32-canonical (verbatim passing chain) ----------
__global__ __launch_bounds__(192) void k_epi(const double* __restrict__ sj,
                                             float* __restrict__ vout,
                                             float* __restrict__ idxout, int b0) {
#pragma clang fp contract(off)
  __shared__ float vsh[160];
  __shared__ float len32[10];
  int bl = blockIdx.x;
  int tid = threadIdx.x;
  const double* sp = sj + (size_t)bl * 160;
  if (tid < 10) {
    float s32[16], a[16];
#pragma unroll
    for (int o = 0; o < 16; o++) { s32[o] = (float)sp[tid * 16 + o]; a[o] = s32[o] * s32[o]; }
    float r[8];
#pragma unroll
    for (int k = 0; k < 8; k++) r[k] = a[k] + a[k + 8];
    float ns = ((r[0] + r[1]) + (r[2] + r[3])) + ((r[4] + r[5]) + (r[6] + r[7]));
    float A = ns / (1.0f + ns);
    float D = 0.001f + sqrtf(ns);
#pragma unroll
    for (int o = 0; o < 16; o++) {
      float v = A * (s32[o] / D);
      vsh[tid * 16 + o] = v;
      a[o] = v * v;
    }
#pragma unroll
    for (int k = 0; k < 8; k++) r[k] = a[k] + a[k + 8];
    float nv = ((r[0] + r[1]) + (r[2] + r[3])) + ((r[4] + r[5]) + (r[6] + r[7]));
    len32[tid] = sqrtf(nv);
  }
  __syncthreads();
  if (tid < 160) vout[(size_t)(b0 + bl) * 160 + tid] = vsh[tid];
  if (tid == 0) {
    float mx = len32[0];
    for (int jj = 1; jj < 10; jj++) mx = fmaxf(mx, len32[jj]);
    float e[10];
    for (int jj = 0; jj < 10; jj++) e[jj] = (float)exp((double)(len32[jj] - mx));
    float ssum = ((e[0] + e[1]) + (e[2] + e[3])) + ((e[4] + e[5]) + (e[6] + e[7]));
    ssum = ssum + e[8];
    ssum = ssum + e[9];
    int best = 0;
    float bst = e[0] / ssum;
    for (int jj = 1; jj < 10; jj++) {
      float p = e[jj] / ssum;
      if (p > bst) { bst = p; best = jj; }
    }
    idxout[b0 + bl] = (float)best;
  }
}

// ---------------- decoder layer 1 (masked input has only 16 nonzeros) -----------
__global__ __launch_bounds__(256) void k_z1(const float* __restrict__ vout,
                                            const int* __restrict__ targets,
                                            const float* __restrict__ W1,
                                            const float* __restrict__ b1,
                                            float* __restrict__ z1) {
  int id = blockIdx.x * 256 + threadIdx.x;
  int b = id >> 9, n = id & 511;
  int t = targets[b];
  float acc = b1[n];
  const float* wr = W1 + (size_t)n * 160 + t * 16;
  const float* vr = vout + (size_t)b * 160 + t * 16;
#pragma unroll
  for (int o = 0; o < 16; o++) acc += wr[o] * vr[o];
  z1[id] = fmaxf(acc, 0.f);
}

// ---------------- generic fp32 GEMM: out[b,n] = act(Z[b,:]·W[n,:] + bias[n]) ----
template <int ACT>
__global__ __launch_bounds__(256) void k_gemm_act(const float* __restrict__ Z,
                                                  const float* __restrict__ W,
                                                  const float* __restrict__ bias,
                                                  float* __restrict__ out, int N, int K) {
  __shared__ float Zt[64][17];
  __shared__ float Wt[64][17];
  int b0 = blockIdx.x * 64;
  int n0 = blockIdx.y * 64;
  int tid = threadIdx.x;
  int ty = tid >> 4, tx = tid & 15;
  int lr = tid >> 2, lc = (tid & 3) * 4;
  float acc[4][4] = {};
  for (int k0 = 0; k0 < K; k0 += 16) {
    __syncthreads();
    f32x4 zv = *(const f32x4*)(Z + (size_t)(b0 + lr) * K + k0 + lc);
    f32x4 wv = {0.f, 0.f, 0.f, 0.f};
    if (n0 + lr < N) wv = *(const f32x4*)(W + (size_t)(n0 + lr) * K + k0 + lc);
    Zt[lr][lc + 0] = zv.x; Zt[lr][lc + 1] = zv.y; Zt[lr][lc + 2] = zv.z; Zt[lr][lc + 3] = zv.w;
    Wt[lr][lc + 0] = wv.x; Wt[lr][lc + 1] = wv.y; Wt[lr][lc + 2] = wv.z; Wt[lr][lc + 3] = wv.w;
    __syncthreads();
#pragma unroll
    for (int kk = 0; kk < 16; kk++) {
      float av[4], bw[4];
#pragma unroll
      for (int i = 0; i < 4; i++) av[i] = Zt[ty * 4 + i][kk];
#pragma unroll
      for (int i = 0; i < 4; i++) bw[i] = Wt[tx * 4 + i][kk];
#pragma unroll
      for (int i = 0; i < 4; i++)
#pragma unroll
        for (int jj = 0; jj < 4; jj++) acc[i][jj] += av[i] * bw[jj];
    }
  }
#pragma unroll
  for (int i = 0; i < 4; i++)
#pragma unroll
    for (int jj = 0; jj < 4; jj++) {
      int bb = b0 + ty * 4 + i;
      int n = n0 + tx * 4 + jj;
      if (n < N) {
        float v = acc[i][jj] + bias[n];
        out[(size_t)bb * N + n] = (ACT == 0) ? fmaxf(v, 0.f) : 1.f / (1.f + __expf(-v));
      }
    }
}

extern "C" void kernel_launch(void* const* d_in, const int* in_sizes, int n_in,
                              void* d_out, int out_size, void* d_ws, size_t ws_size,
                              hipStream_t stream) {
  const float* x       = (const float*)d_in[0];
  const int* targets   = (const int*)d_in[1];
  const float* Wc      = (const float*)d_in[2];
  const float* bc      = (const float*)d_in[3];
  const float* Wp      = (const float*)d_in[4];
  const float* bp      = (const float*)d_in[5];
  const float* Wd      = (const float*)d_in[6];
  const float* W1      = (const float*)d_in[7];
  const float* b1      = (const float*)d_in[8];
  const float* W2      = (const float*)d_in[9];
  const float* b2      = (const float*)d_in[10];
  const float* W3      = (const float*)d_in[11];
  const float* b3      = (const float*)d_in[12];

  char* ws = (char*)d_ws;
  const size_t MB = 1024 * 1024;
  // Conv phase:
  //   wT32 [0, 20.25)      fp32 [k][n] weights
  //   h64  [21, 21+chunk)  19x19x256 f64 per image, chunk-local
  //   u64  above h         conv2 out full batch -> squashed in place
  // Halves (256 imgs):  h 189.3 -> u @211, peak 247 MiB (needs ws >= 248).
  // Thirds (<=172 imgs): h 127.1 -> u @149, peak 185 MiB (within proven 213).
  float* wT32 = (float*)ws;
  double* h64 = (double*)(ws + 21 * MB);
  bool halves = (ws_size >= (size_t)248 * MB);
  double* u64 = (double*)(ws + (halves ? 211 : 149) * MB);
  // Routing phase (wT32/h64 dead): all below 149 MiB.
  double* uhat64 = (double*)(ws);             // 90   [0,90)
  double* bij64  = (double*)(ws + 90 * MB);   // 5.63 [90,96)
  double* cij64  = (double*)(ws + 96 * MB);   // 5.63 [96,102)
  double* sj64   = (double*)(ws + 102 * MB);  // 0.08
  float* z1      = (float*)(ws + 103 * MB);   // 1 MiB
  float* z2      = (float*)(ws + 104 * MB);   // 2 MiB

  float* vout   = (float*)d_out;                  // [512,10,16]
  float* recon  = (float*)d_out + 81920;          // [512,784]
  float* idxout = (float*)d_out + 81920 + 401408; // [512]

  k_wkn<<<4096, 256, 0, stream>>>(Wp, wT32);
  if (halves) {
    // 2 chunks of 256 imgs: 144 m-tiles x 4 n-tiles = 576 blocks/launch
    for (int L = 0; L < 2; L++) {
      int imgLo = L * 256;
      k_conv1_19<<<512, 256, 0, stream>>>(x + (size_t)imgLo * 784, Wc, bc, h64);
      k_conv2_t<<<dim3(144, 4), 512, 0, stream>>>(h64, wT32, u64, 9216 * L, imgLo);
    }
  } else {
    // 3 chunks of 6144 m-rows (<=172 imgs): 96 x 4 = 384 blocks/launch
    const int iLo[3] = {0, 170, 341};
    const int iHi[3] = {171, 342, 512};
    for (int L = 0; L < 3; L++) {
      int cnt = iHi[L] - iLo[L];
      k_conv1_19<<<cnt * 2, 256, 0, stream>>>(x + (size_t)iLo[L] * 784, Wc, bc, h64);
      k_conv2_t<<<dim3(96, 4), 512, 0, stream>>>(h64, wT32, u64, 6144 * L, iLo[L]);
    }
  }
  k_squash_ip<<<2304, 256, 0, stream>>>(u64, bp);
  for (int e = 0; e < 8; e++) {
    int b0 = e * 64;
    k_uhat64<<<1152, 320, 0, stream>>>(u64, Wd, uhat64, b0);
    k_route_s<0><<<dim3(64, 10), 256, 0, stream>>>(uhat64, cij64, sj64);
    k_route_b<true><<<dim3(64, 9), 256, 0, stream>>>(uhat64, sj64, bij64);
    k_cij<<<dim3(64, 6), 192, 0, stream>>>(bij64, cij64);
    k_route_s<1><<<dim3(64, 10), 256, 0, stream>>>(uhat64, cij64, sj64);
    k_route_b<false><<<dim3(64, 9), 256, 0, stream>>>(uhat64, sj64, bij64);
    k_cij<<<dim3(64, 6), 192, 0, stream>>>(bij64, cij64);
    k_route_s<2><<<dim3(64, 10), 256, 0, stream>>>(uhat64, cij64, sj64);
    k_epi<<<64, 192, 0, stream>>>(sj64, vout, idxout, b0);
  }
  k_z1<<<1024, 256, 0, stream>>>(vout, targets, W1, b1, z1);
  k_gemm_act<0><<<dim3(8, 16), 256, 0, stream>>>(z1, W2, b2, z2, 1024, 512);
  k_gemm_act<1><<<dim3(8, 13), 256, 0, stream>>>(z2, W3, b3, recon, 784, 1024);
}

// Round 6
// 8354.411 us; speedup vs baseline: 7.1151x; 1.3755x over previous
//
#include <hip/hip_runtime.h>
#include <math.h>

typedef __attribute__((ext_vector_type(2))) double f64x2;
typedef __attribute__((ext_vector_type(2))) float f32x2;
typedef __attribute__((ext_vector_type(4))) float f32x4;

// ---------------- Wp -> wT fp32, layout [k][n], k=(ky*9+kx)*256+ci --------------
// Raw fp32 values; (double)f32 at use is exact -> products bit-identical.
__global__ __launch_bounds__(256) void k_wkn(const float* __restrict__ Wp,
                                             float* __restrict__ wT) {
  const int total = 20736 * 256;
  for (int gid = blockIdx.x * 256 + threadIdx.x; gid < total; gid += gridDim.x * 256) {
    int k = gid >> 8, n = gid & 255;
    int t = k >> 8, ci = k & 255;
    wT[gid] = Wp[(size_t)n * 20736 + ci * 81 + t];
  }
}

// ---------------- Conv1: 1->256 k9 s1, fp64, out [img][y][x][256], 19x19 --------
__global__ __launch_bounds__(256) void k_conv1_19(const float* __restrict__ x,
                                                  const float* __restrict__ Wc,
                                                  const float* __restrict__ bc,
                                                  double* __restrict__ h) {
  int b = blockIdx.x >> 1;
  int rh = (blockIdx.x & 1) * 10;
  int re = rh ? 19 : 10;
  int oc = threadIdx.x;
  __shared__ float xs[784];
  for (int i = threadIdx.x; i < 784; i += 256) xs[i] = x[(size_t)b * 784 + i];
  __syncthreads();
  float w[81];
#pragma unroll
  for (int t = 0; t < 81; t++) w[t] = Wc[(size_t)oc * 81 + t];
  double bias = (double)bc[oc];
  for (int oh = rh; oh < re; oh++) {
    for (int ow4 = 0; ow4 < 20; ow4 += 4) {
      double a0 = bias, a1 = bias, a2 = bias, a3 = bias;
#pragma unroll
      for (int ky = 0; ky < 9; ky++) {
        const float* xr = &xs[(oh + ky) * 28 + ow4];
#pragma unroll
        for (int kx = 0; kx < 9; kx++) {
          double wv = (double)w[ky * 9 + kx];
          a0 += wv * (double)xr[kx + 0];
          a1 += wv * (double)xr[kx + 1];
          a2 += wv * (double)xr[kx + 2];
          a3 += wv * (double)xr[kx + 3];
        }
      }
      size_t base = ((size_t)(b * 19 + oh) * 19 + ow4) * 256 + oc;
      h[base + 0]   = fmax(a0, 0.0);
      h[base + 256] = fmax(a1, 0.0);
      h[base + 512] = fmax(a2, 0.0);
      if (ow4 < 16) h[base + 768] = fmax(a3, 0.0);  // skip col 19
    }
  }
}

// ---------------- Conv2 implicit GEMM, fp64 VALU, conflict-free dbuf LDS --------
// Tile 64m x 32n, 256 thr (4 waves), thread tile 2m x 4n, BK=16.
// Thirds grid: dim3(96,8) = 768 blocks = exactly 3 blocks/CU (12 waves).
// B row layout pair-interleaved: pair p (n=2p,2p+1) at byte (p&1)*128+(p>>1)*16
// -> compute reads hit banks {0,4,...,28} exactly once per instr (conflict-free).
// Single barrier per K-step via double buffer (write-next, compute-cur, barrier).
// Per-output accumulation: k ascending, one sequential fma per k -> bit-identical.
__global__ __launch_bounds__(256, 3) void k_conv2_d(const double* __restrict__ h,
                                                    const float* __restrict__ wT,
                                                    double* __restrict__ uraw,
                                                    int mG0, int imgLo) {
  __shared__ __align__(16) double AsT[2][16][66];  // [buf][k][m]
  __shared__ __align__(16) double Bs[2][16][32];   // [buf][k][pair-interleaved n]
  int tid = threadIdx.x;
  int m0 = blockIdx.x * 64, n0 = blockIdx.y * 32;

  // A staging: 64m x 16k / 256thr -> 4 consecutive k per thread (2 f64x2)
  int sm = tid >> 2, skA = (tid & 3) * 4;
  int mGa = mG0 + m0 + sm;
  int imga = mGa / 36, spa = mGa % 36;
  size_t abase = ((size_t)((imga - imgLo) * 361 + (spa / 6) * 38 + (spa % 6) * 2)) * 256;
  // B staging: 16k x 16 pairs / 256thr -> 1 pair per thread
  int kb = tid >> 4, pB = tid & 15;
  int bcol = (pB & 1) * 16 + (pB >> 1) * 2;
  // compute coords: ty 0..31 (2 m's), tx 0..7 (4 n's = pairs 2tx,2tx+1)
  int ty = tid >> 3, tx = tid & 7;

  double acc[2][4];
#pragma unroll
  for (int i = 0; i < 2; i++)
#pragma unroll
    for (int j = 0; j < 4; j++) acc[i][j] = 0.0;

  auto gofs = [](int k) -> size_t {
    int t = k >> 8, ci = k & 255;
    return (size_t)((t / 9) * 19 + (t % 9)) * 256 + ci;
  };

  f64x2 pa0, pa1;
  f32x2 pb;
  auto loadreg = [&](int ks) {
    const double* ga = h + abase + gofs(ks * 16 + skA);
    pa0 = *(const f64x2*)(ga);
    pa1 = *(const f64x2*)(ga + 2);
    pb = *(const f32x2*)(wT + (size_t)(ks * 16 + kb) * 256 + n0 + pB * 2);
  };
  auto writebuf = [&](int buf) {
    AsT[buf][skA + 0][sm] = pa0.x;
    AsT[buf][skA + 1][sm] = pa0.y;
    AsT[buf][skA + 2][sm] = pa1.x;
    AsT[buf][skA + 3][sm] = pa1.y;
    *(f64x2*)&Bs[buf][kb][bcol] = f64x2{(double)pb.x, (double)pb.y};
  };

  loadreg(0);
  writebuf(0);
  loadreg(1);
  __syncthreads();

  int cur = 0;
  for (int ks = 0; ks < 1296; ks++) {
    if (ks + 1 < 1296) writebuf(cur ^ 1);   // safe: barrier at end of ks-1 ordered this
    if (ks + 2 < 1296) loadreg(ks + 2);
#pragma unroll
    for (int kk = 0; kk < 16; kk++) {
      f64x2 av  = *(const f64x2*)&AsT[cur][kk][ty * 2];
      f64x2 b01 = *(const f64x2*)&Bs[cur][kk][tx * 2];
      f64x2 b23 = *(const f64x2*)&Bs[cur][kk][16 + tx * 2];
      acc[0][0] = fma(av.x, b01.x, acc[0][0]);
      acc[0][1] = fma(av.x, b01.y, acc[0][1]);
      acc[0][2] = fma(av.x, b23.x, acc[0][2]);
      acc[0][3] = fma(av.x, b23.y, acc[0][3]);
      acc[1][0] = fma(av.y, b01.x, acc[1][0]);
      acc[1][1] = fma(av.y, b01.y, acc[1][1]);
      acc[1][2] = fma(av.y, b23.x, acc[1][2]);
      acc[1][3] = fma(av.y, b23.y, acc[1][3]);
    }
    __syncthreads();
    cur ^= 1;
  }

  // out[b][ch][sp]: capsule features = 8 consecutive doubles (ch*36+sp = cap*8+feat)
#pragma unroll
  for (int i = 0; i < 2; i++) {
    int mG = mG0 + m0 + ty * 2 + i;
    int img = mG / 36, sp = mG % 36;
    size_t ob = (size_t)img * 9216 + sp;
#pragma unroll
    for (int j = 0; j < 4; j++) {
      int n = n0 + tx * 4 + j;
      uraw[ob + (size_t)n * 36] = acc[i][j];
    }
  }
}

// ---------------- squash of primary capsules, fp64, IN PLACE --------------------
__global__ __launch_bounds__(256) void k_squash_ip(double* __restrict__ u,
                                                   const float* __restrict__ bp) {
  int idx = blockIdx.x * 256 + threadIdx.x;  // (b,c): 512*1152
  int bl = idx / 1152, c = idx % 1152;
  size_t base = ((size_t)bl * 1152 + c) * 8;
  double v[8];
  double ns = 0.0;
#pragma unroll
  for (int i = 0; i < 8; i++) {
    int f = c * 8 + i;
    int ch = f / 36;
    double val = u[base + i] + (double)bp[ch];
    v[i] = val;
    ns += val * val;
  }
  double sc = (ns / (1.0 + ns)) / (0.001 + sqrt(ns));
#pragma unroll
  for (int i = 0; i < 8; i++) u[base + i] = v[i] * sc;
}

// ---------------- u_hat fp64, eighth batch (bl in [0,64)) -----------------------
__global__ __launch_bounds__(320) void k_uhat64(const double* __restrict__ u,
                                                const float* __restrict__ Wd,
                                                double* __restrict__ uhat, int b0) {
  int c = blockIdx.x;
  int t = threadIdx.x;
  int jo = t % 160, half = t / 160;
  double w[8];
#pragma unroll
  for (int i = 0; i < 8; i++) w[i] = (double)Wd[((size_t)c * 160 + jo) * 8 + i];
  for (int it = 0; it < 32; it++) {
    int bl = it * 2 + half;
    const double* up = u + ((size_t)(b0 + bl) * 1152 + c) * 8;
    double s = 0.0;
#pragma unroll
    for (int i = 0; i < 8; i++) s += w[i] * up[i];
    uhat[((size_t)bl * 1152 + c) * 160 + jo] = s;
  }
}

// ---------------- c_ij = softmax(b_ij) fp64, wide grid --------------------------
__global__ __launch_bounds__(192) void k_cij(const double* __restrict__ bij,
                                             double* __restrict__ cij) {
  int bl = blockIdx.x;
  int c = blockIdx.y * 192 + threadIdx.x;  // 6*192 = 1152
  const double* bp_ = bij + ((size_t)bl * 1152 + c) * 10;
  double bv[10], mx = -1e300;
#pragma unroll
  for (int j = 0; j < 10; j++) { bv[j] = bp_[j]; mx = fmax(mx, bv[j]); }
  double s = 0.0;
#pragma unroll
  for (int j = 0; j < 10; j++) { bv[j] = exp(bv[j] - mx); s += bv[j]; }
  double inv = 1.0 / s;
  double* cp = cij + ((size_t)bl * 1152 + c) * 10;
#pragma unroll
  for (int j = 0; j < 10; j++) cp[j] = bv[j] * inv;
}

// ---------------- routing s_j pass fp64, wide coalesced grid (bl x j) -----------
template <int IT>
__global__ __launch_bounds__(256) void k_route_s(const double* __restrict__ uhat,
                                                 const double* __restrict__ cij,
                                                 double* __restrict__ sj) {
  int bl = blockIdx.x, j = blockIdx.y;
  int tid = threadIdx.x;
  int o = tid & 15, cl = tid >> 4;
  double acc = 0.0;
  const double* up = uhat + (size_t)bl * 1152 * 160 + j * 16 + o;
  if (IT == 0) {
    for (int c = cl; c < 1152; c += 16) acc += 0.1 * up[(size_t)c * 160];
  } else {
    const double* cp = cij + (size_t)bl * 1152 * 10 + j;
    for (int c = cl; c < 1152; c += 16) acc += cp[(size_t)c * 10] * up[(size_t)c * 160];
  }
  __shared__ double red[256];
  red[tid] = acc;
  __syncthreads();
#pragma unroll
  for (int s = 128; s >= 16; s >>= 1) {
    if (tid < s) red[tid] += red[tid + s];
    __syncthreads();
  }
  if (tid < 16) sj[(size_t)bl * 160 + j * 16 + tid] = red[tid];
}

// ---------------- agreement update b_ij fp64, wide grid -------------------------
template <bool FIRST>
__global__ __launch_bounds__(256) void k_route_b(const double* __restrict__ uhat,
                                                 const double* __restrict__ sj,
                                                 double* __restrict__ bij) {
  __shared__ double sl[160];
  int bl = blockIdx.x;
  int tid = threadIdx.x;
  if (tid < 160) sl[tid] = sj[(size_t)bl * 160 + tid];
  __syncthreads();
  int c = blockIdx.y * 128 + (tid >> 1);
  int j0 = (tid & 1) * 5;
  const double* up = uhat + ((size_t)bl * 1152 + c) * 160;
  double* bp_ = bij + ((size_t)bl * 1152 + c) * 10;
#pragma unroll
  for (int jj = 0; jj < 5; jj++) {
    int j = j0 + jj;
    double dot = 0.0;
#pragma unroll
    for (int oo = 0; oo < 16; oo++) dot += sl[j * 16 + oo] * up[j * 16 + oo];
    bp_[j] = (FIRST ? 0.0 : bp_[j]) + dot;
  }
}

// ---------------- epilogue: np-fp32-canonical (verbatim passing chain) ----------
__global__ __launch_bounds__(192) void k_epi(const double* __restrict__ sj,
                                             float* __restrict__ vout,
                                             float* __restrict__ idxout, int b0) {
#pragma clang fp contract(off)
  __shared__ float vsh[160];
  __shared__ float len32[10];
  int bl = blockIdx.x;
  int tid = threadIdx.x;
  const double* sp = sj + (size_t)bl * 160;
  if (tid < 10) {
    float s32[16], a[16];
#pragma unroll
    for (int o = 0; o < 16; o++) { s32[o] = (float)sp[tid * 16 + o]; a[o] = s32[o] * s32[o]; }
    float r[8];
#pragma unroll
    for (int k = 0; k < 8; k++) r[k] = a[k] + a[k + 8];
    float ns = ((r[0] + r[1]) + (r[2] + r[3])) + ((r[4] + r[5]) + (r[6] + r[7]));
    float A = ns / (1.0f + ns);
    float D = 0.001f + sqrtf(ns);
#pragma unroll
    for (int o = 0; o < 16; o++) {
      float v = A * (s32[o] / D);
      vsh[tid * 16 + o] = v;
      a[o] = v * v;
    }
#pragma unroll
    for (int k = 0; k < 8; k++) r[k] = a[k] + a[k + 8];
    float nv = ((r[0] + r[1]) + (r[2] + r[3])) + ((r[4] + r[5]) + (r[6] + r[7]));
    len32[tid] = sqrtf(nv);
  }
  __syncthreads();
  if (tid < 160) vout[(size_t)(b0 + bl) * 160 + tid] = vsh[tid];
  if (tid == 0) {
    float mx = len32[0];
    for (int jj = 1; jj < 10; jj++) mx = fmaxf(mx, len32[jj]);
    float e[10];
    for (int jj = 0; jj < 10; jj++) e[jj] = (float)exp((double)(len32[jj] - mx));
    float ssum = ((e[0] + e[1]) + (e[2] + e[3])) + ((e[4] + e[5]) + (e[6] + e[7]));
    ssum = ssum + e[8];
    ssum = ssum + e[9];
    int best = 0;
    float bst = e[0] / ssum;
    for (int jj = 1; jj < 10; jj++) {
      float p = e[jj] / ssum;
      if (p > bst) { bst = p; best = jj; }
    }
    idxout[b0 + bl] = (float)best;
  }
}

// ---------------- decoder layer 1 (masked input has only 16 nonzeros) -----------
__global__ __launch_bounds__(256) void k_z1(const float* __restrict__ vout,
                                            const int* __restrict__ targets,
                                            const float* __restrict__ W1,
                                            const float* __restrict__ b1,
                                            float* __restrict__ z1) {
  int id = blockIdx.x * 256 + threadIdx.x;
  int b = id >> 9, n = id & 511;
  int t = targets[b];
  float acc = b1[n];
  const float* wr = W1 + (size_t)n * 160 + t * 16;
  const float* vr = vout + (size_t)b * 160 + t * 16;
#pragma unroll
  for (int o = 0; o < 16; o++) acc += wr[o] * vr[o];
  z1[id] = fmaxf(acc, 0.f);
}

// ---------------- generic fp32 GEMM: out[b,n] = act(Z[b,:]·W[n,:] + bias[n]) ----
template <int ACT>
__global__ __launch_bounds__(256) void k_gemm_act(const float* __restrict__ Z,
                                                  const float* __restrict__ W,
                                                  const float* __restrict__ bias,
                                                  float* __restrict__ out, int N, int K) {
  __shared__ float Zt[64][17];
  __shared__ float Wt[64][17];
  int b0 = blockIdx.x * 64;
  int n0 = blockIdx.y * 64;
  int tid = threadIdx.x;
  int ty = tid >> 4, tx = tid & 15;
  int lr = tid >> 2, lc = (tid & 3) * 4;
  float acc[4][4] = {};
  for (int k0 = 0; k0 < K; k0 += 16) {
    __syncthreads();
    f32x4 zv = *(const f32x4*)(Z + (size_t)(b0 + lr) * K + k0 + lc);
    f32x4 wv = {0.f, 0.f, 0.f, 0.f};
    if (n0 + lr < N) wv = *(const f32x4*)(W + (size_t)(n0 + lr) * K + k0 + lc);
    Zt[lr][lc + 0] = zv.x; Zt[lr][lc + 1] = zv.y; Zt[lr][lc + 2] = zv.z; Zt[lr][lc + 3] = zv.w;
    Wt[lr][lc + 0] = wv.x; Wt[lr][lc + 1] = wv.y; Wt[lr][lc + 2] = wv.z; Wt[lr][lc + 3] = wv.w;
    __syncthreads();
#pragma unroll
    for (int kk = 0; kk < 16; kk++) {
      float av[4], bw[4];
#pragma unroll
      for (int i = 0; i < 4; i++) av[i] = Zt[ty * 4 + i][kk];
#pragma unroll
      for (int i = 0; i < 4; i++) bw[i] = Wt[tx * 4 + i][kk];
#pragma unroll
      for (int i = 0; i < 4; i++)
#pragma unroll
        for (int jj = 0; jj < 4; jj++) acc[i][jj] += av[i] * bw[jj];
    }
  }
#pragma unroll
  for (int i = 0; i < 4; i++)
#pragma unroll
    for (int jj = 0; jj < 4; jj++) {
      int bb = b0 + ty * 4 + i;
      int n = n0 + tx * 4 + jj;
      if (n < N) {
        float v = acc[i][jj] + bias[n];
        out[(size_t)bb * N + n] = (ACT == 0) ? fmaxf(v, 0.f) : 1.f / (1.f + __expf(-v));
      }
    }
}

extern "C" void kernel_launch(void* const* d_in, const int* in_sizes, int n_in,
                              void* d_out, int out_size, void* d_ws, size_t ws_size,
                              hipStream_t stream) {
  const float* x       = (const float*)d_in[0];
  const int* targets   = (const int*)d_in[1];
  const float* Wc      = (const float*)d_in[2];
  const float* bc      = (const float*)d_in[3];
  const float* Wp      = (const float*)d_in[4];
  const float* bp      = (const float*)d_in[5];
  const float* Wd      = (const float*)d_in[6];
  const float* W1      = (const float*)d_in[7];
  const float* b1      = (const float*)d_in[8];
  const float* W2      = (const float*)d_in[9];
  const float* b2      = (const float*)d_in[10];
  const float* W3      = (const float*)d_in[11];
  const float* b3      = (const float*)d_in[12];

  char* ws = (char*)d_ws;
  const size_t MB = 1024 * 1024;
  // Conv phase (thirds of <=172 imgs):
  //   wT32 [0, 20.25)    fp32 [k][n] weights
  //   h64  [21, 148.2)   19x19x256 f64 per image, chunk-local
  //   u64  [149, 185)    conv2 out full batch -> squashed in place
  // Peak 185 MiB (proven-safe envelope: 213).
  float* wT32 = (float*)ws;
  double* h64 = (double*)(ws + 21 * MB);
  double* u64 = (double*)(ws + 149 * MB);
  // Routing phase (wT32/h64 dead): all below 149 MiB.
  double* uhat64 = (double*)(ws);             // 90   [0,90)
  double* bij64  = (double*)(ws + 90 * MB);   // 5.63 [90,96)
  double* cij64  = (double*)(ws + 96 * MB);   // 5.63 [96,102)
  double* sj64   = (double*)(ws + 102 * MB);  // 0.08
  float* z1      = (float*)(ws + 103 * MB);   // 1 MiB
  float* z2      = (float*)(ws + 104 * MB);   // 2 MiB

  float* vout   = (float*)d_out;                  // [512,10,16]
  float* recon  = (float*)d_out + 81920;          // [512,784]
  float* idxout = (float*)d_out + 81920 + 401408; // [512]

  k_wkn<<<4096, 256, 0, stream>>>(Wp, wT32);
  // 3 chunks of 6144 m-rows (<=172 imgs): 96 m-tiles x 8 n-tiles = 768 blocks
  const int iLo[3] = {0, 170, 341};
  const int iHi[3] = {171, 342, 512};
  for (int L = 0; L < 3; L++) {
    int cnt = iHi[L] - iLo[L];
    k_conv1_19<<<cnt * 2, 256, 0, stream>>>(x + (size_t)iLo[L] * 784, Wc, bc, h64);
    k_conv2_d<<<dim3(96, 8), 256, 0, stream>>>(h64, wT32, u64, 6144 * L, iLo[L]);
  }
  k_squash_ip<<<2304, 256, 0, stream>>>(u64, bp);
  for (int e = 0; e < 8; e++) {
    int b0 = e * 64;
    k_uhat64<<<1152, 320, 0, stream>>>(u64, Wd, uhat64, b0);
    k_route_s<0><<<dim3(64, 10), 256, 0, stream>>>(uhat64, cij64, sj64);
    k_route_b<true><<<dim3(64, 9), 256, 0, stream>>>(uhat64, sj64, bij64);
    k_cij<<<dim3(64, 6), 192, 0, stream>>>(bij64, cij64);
    k_route_s<1><<<dim3(64, 10), 256, 0, stream>>>(uhat64, cij64, sj64);
    k_route_b<false><<<dim3(64, 9), 256, 0, stream>>>(uhat64, sj64, bij64);
    k_cij<<<dim3(64, 6), 192, 0, stream>>>(bij64, cij64);
    k_route_s<2><<<dim3(64, 10), 256, 0, stream>>>(uhat64, cij64, sj64);
    k_epi<<<64, 192, 0, stream>>>(sj64, vout, idxout, b0);
  }
  k_z1<<<1024, 256, 0, stream>>>(vout, targets, W1, b1, z1);
  k_gemm_act<0><<<dim3(8, 16), 256, 0, stream>>>(z1, W2, b2, z2, 1024, 512);
  k_gemm_act<1><<<dim3(8, 13), 256, 0, stream>>>(z2, W3, b3, recon, 784, 1024);
}